// Round 1
// baseline (325.469 us; speedup 1.0000x reference)
//
#include <hip/hip_runtime.h>
#include <stdint.h>

// topk(values+indices), x: (2,4096,50257) fp32, k=50, last axis, largest, sorted.
// d_out layout (harness reads flat float32): [rows*k values][rows*k indices-as-float]
//
// Strategy: one block per row. Single streaming pass with coalesced float4
// loads; elements above a threshold are appended to an LDS candidate buffer.
// Threshold starts at 2.5 (generous for N(0,1); ~312 candidates/row expected,
// need >=50, cap 2048) and is bisected in ordered-uint space if the count
// falls outside [k, CAP] (never triggers for this input; rescans hit L2).
// Candidates are bitonic-sorted in LDS by (value desc, index asc) -- the
// lowest-index-first tie-break matches jax.lax.top_k / numpy stable sort.

#define TPB 256
#define CAP 2048

__device__ __forceinline__ unsigned ordf(float f) {
  unsigned s = __float_as_uint(f);
  return (s & 0x80000000u) ? ~s : (s | 0x80000000u);
}
__device__ __forceinline__ float unordf(unsigned u) {
  unsigned s = (u & 0x80000000u) ? (u ^ 0x80000000u) : ~u;
  return __uint_as_float(s);
}

__global__ __launch_bounds__(TPB) void topk_rowselect_kernel(
    const float* __restrict__ x, float* __restrict__ out,
    int rows, int V, int k, int out_half) {
  const int row = blockIdx.x;
  const int tid = threadIdx.x;
  if (row >= rows) return;
  const float* rp = x + (size_t)row * (size_t)V;

  __shared__ float cv[CAP];
  __shared__ unsigned ci[CAP];
  __shared__ int s_cnt;

  // Per-row 16B alignment handling (V odd -> row bases cycle mod 16).
  unsigned mis = (unsigned)((size_t)rp & 15u);
  int head = (int)(((16u - mis) & 15u) >> 2);
  if (head > V) head = V;
  int nvec = (V - head) >> 2;
  int tail_start = head + nvec * 4;
  const float4* vp = (const float4*)(rp + head);

  unsigned lo = 0u, hi = 0xFFFFFFFFu;
  unsigned tu = ordf(2.5f);
  int cnt = 0;

  for (int attempt = 0; attempt < 48; ++attempt) {
    if (tid == 0) s_cnt = 0;
    __syncthreads();
    float thr = unordf(tu);

    for (int i = tid; i < head; i += TPB) {
      float v = rp[i];
      if (v > thr) { int p = atomicAdd(&s_cnt, 1); if (p < CAP) { cv[p] = v; ci[p] = (unsigned)i; } }
    }
    for (int i = tail_start + tid; i < V; i += TPB) {
      float v = rp[i];
      if (v > thr) { int p = atomicAdd(&s_cnt, 1); if (p < CAP) { cv[p] = v; ci[p] = (unsigned)i; } }
    }
    for (int j = tid; j < nvec; j += TPB) {
      float4 v = vp[j];
      int base = head + 4 * j;
      if (v.x > thr) { int p = atomicAdd(&s_cnt, 1); if (p < CAP) { cv[p] = v.x; ci[p] = (unsigned)(base + 0); } }
      if (v.y > thr) { int p = atomicAdd(&s_cnt, 1); if (p < CAP) { cv[p] = v.y; ci[p] = (unsigned)(base + 1); } }
      if (v.z > thr) { int p = atomicAdd(&s_cnt, 1); if (p < CAP) { cv[p] = v.z; ci[p] = (unsigned)(base + 2); } }
      if (v.w > thr) { int p = atomicAdd(&s_cnt, 1); if (p < CAP) { cv[p] = v.w; ci[p] = (unsigned)(base + 3); } }
    }
    __syncthreads();
    cnt = s_cnt;
    // All threads compute identical control flow from shared cnt.
    if (cnt >= k && cnt <= CAP) break;
    if (hi <= lo + 1u) break;                 // pathological ties: accept
    if (cnt > CAP) lo = tu; else hi = tu;
    unsigned mid = (unsigned)(((unsigned long long)lo + (unsigned long long)hi) >> 1);
    if (mid == tu) break;
    tu = mid;
    __syncthreads();                          // protect s_cnt reset next pass
  }
  if (cnt > CAP) cnt = CAP;

  // Pad to power of two for bitonic sort.
  int np2 = 64;
  while (np2 < cnt) np2 <<= 1;
  for (int i = cnt + tid; i < np2; i += TPB) { cv[i] = -INFINITY; ci[i] = 0xFFFFFFFFu; }
  __syncthreads();

  // Bitonic sort: final order descending by value, ascending index on ties.
  for (int sz = 2; sz <= np2; sz <<= 1) {
    for (int st = sz >> 1; st > 0; st >>= 1) {
      for (int t = tid; t < (np2 >> 1); t += TPB) {
        int i = ((t & ~(st - 1)) << 1) | (t & (st - 1));
        int j = i | st;
        bool segDesc = ((i & sz) == 0);
        float va = cv[i], vb = cv[j];
        unsigned ia = ci[i], ib = ci[j];
        bool aFirst = (va > vb) || (va == vb && ia < ib);
        if (segDesc ? !aFirst : aFirst) {
          cv[i] = vb; cv[j] = va;
          ci[i] = ib; ci[j] = ia;
        }
      }
      __syncthreads();
    }
  }

  float* out_vals = out;
  float* out_idx  = out + out_half;
  for (int t = tid; t < k; t += TPB) {
    out_vals[(size_t)row * k + t] = cv[t];
    out_idx[(size_t)row * k + t]  = (float)ci[t];
  }
}

extern "C" void kernel_launch(void* const* d_in, const int* in_sizes, int n_in,
                              void* d_out, int out_size, void* d_ws, size_t ws_size,
                              hipStream_t stream) {
  const float* x = (const float*)d_in[0];
  // k is a device-side scalar; the instance is fixed (k=50). Derive shapes
  // from sizes so a mismatch fails loudly rather than silently.
  const int k = 50;
  const int out_half = out_size / 2;      // rows * k
  const int rows = out_half / k;          // 8192
  const int V = in_sizes[0] / rows;       // 50257

  dim3 grid(rows), block(TPB);
  hipLaunchKernelGGL(topk_rowselect_kernel, grid, block, 0, stream,
                     x, (float*)d_out, rows, V, k, out_half);
}